// Round 1
// 545.344 us; speedup vs baseline: 1.0607x; 1.0607x over previous
//
#include <hip/hip_runtime.h>

#define NH   4
#define ATT  16
#define COL  64
#define AIS  64
#define SK   200
#define HD   64
#define JP   32          // j-pairs per row
#define AROW 33          // uint (half2) stride per k row: bank=(k+jp)%32 -> 2-way free

typedef _Float16 half2v __attribute__((ext_vector_type(2)));
typedef unsigned int uint32;

static __device__ __forceinline__ half2v u2h(uint32 u) {
    union { uint32 u; half2v h; } x; x.u = u; return x.h;
}

// pack two f32 -> f16x2 as raw uint32
static __device__ __forceinline__ uint32 pk_u32(float a, float b) {
#if __has_builtin(__builtin_amdgcn_cvt_pkrtz)
    union { decltype(__builtin_amdgcn_cvt_pkrtz(0.f, 0.f)) h; uint32 u; } x;
    x.h = __builtin_amdgcn_cvt_pkrtz(a, b);
    return x.u;
#else
    union { half2v h; uint32 u; } x;
    x.h.x = (_Float16)a; x.h.y = (_Float16)b;
    return x.u;
#endif
}

#if __has_builtin(__builtin_amdgcn_fdot2)
#define DOT2(a, b, c) __builtin_amdgcn_fdot2((a), (b), (c), false)
#else
#define DOT2(a, b, c) fmaf((float)(a).x, (float)(b).x, fmaf((float)(a).y, (float)(b).y, (c)))
#endif

// ---------------------------------------------------------------------------
// Fully fused kernel: one block per batch, NO workspace.
//  - issue A-tile loads (13 float4/thread) FIRST, into registers
//  - compute qh = q.Qw (t<64) and qk[h][jp] pairs (t<128) while loads fly
//  - stage A as f16 pairs (26.4 KB, stride 33 -> conflict-free columns)
//  - scores: thread k, A2 b32 reads + qk uint4 LDS broadcasts, 4x fdot2/iter
//  - softmax: wave h owns head h
//  - w[h][j]: A read shared across 4 heads, k split over 4 waves
//  - epilogue: out = (w/denom) . V, V rows L1-hot
// LDS ~35.5 KB -> 4 blocks/CU (16 waves/CU)
// ---------------------------------------------------------------------------
__global__ __launch_bounds__(256, 4)
void fused_attn_kernel(const float* __restrict__ query,
                       const float* __restrict__ action,
                       const float* __restrict__ Qw,
                       const float* __restrict__ Kw,
                       const float* __restrict__ Vw,
                       float* __restrict__ out) {
    __shared__ uint32 A2[SK * AROW];       // 26400 B
    __shared__ float4 p4_s[SK];            // 3200 B
    __shared__ float4 wpart[4][64];        // 4096 B
    __shared__ float4 w4_s[64];            // 1024 B
    __shared__ float  invd_s[NH];
    __shared__ float  qh_s[HD];            // 256 B
    __shared__ __align__(16) uint32 qk4_s[JP * 4];  // [jp][h] f16-pairs, 512 B

    const int b    = blockIdx.x;
    const int t    = threadIdx.x;
    const int lane = t & 63;
    const int wv   = t >> 6;

    // ---- issue A[b] loads early (200x64 fp32 = 3200 float4) ----
    const float4* act4 = (const float4*)(action + (size_t)b * (SK * AIS));
    float4 sv[13];
    #pragma unroll
    for (int i = 0; i < 12; ++i) sv[i] = act4[i * 256 + t];
    if (t < 128) sv[12] = act4[3072 + t];

    // ---- qh[t] = q . Qw[:,t]  (query row wave-uniform -> s_load; Qw L1-hot) ----
    const float* qb = query + (size_t)b * COL;
    if (t < HD) {
        float acc = 0.f;
        #pragma unroll
        for (int c = 0; c < COL; ++c)
            acc = fmaf(qb[c], Qw[c * HD + t], acc);
        qh_s[t] = acc;
    }
    __syncthreads();

    // ---- qk4_s[jp][h] = f16x2( 0.125*qh[h].K[:,2jp], 0.125*qh[h].K[:,2jp+1] ) ----
    if (t < 128) {
        const int h = t >> 5, jp = t & 31;
        float a0 = 0.f, a1 = 0.f;
        #pragma unroll
        for (int d = 0; d < ATT; ++d) {
            const float q = qh_s[h * ATT + d];
            a0 = fmaf(q, Kw[(2 * jp)     * HD + h * ATT + d], a0);
            a1 = fmaf(q, Kw[(2 * jp + 1) * HD + h * ATT + d], a1);
        }
        qk4_s[jp * 4 + h] = pk_u32(a0 * 0.125f, a1 * 0.125f);
    }

    // ---- stage A -> f16 pairs in LDS (consume the early loads) ----
    #pragma unroll
    for (int i = 0; i < 12; ++i) {
        const int idx = i * 256 + t;                 // float4 index
        const float4 v = sv[i];
        const int k   = idx >> 4;                    // 16 float4 per row
        const int jp0 = (idx & 15) * 2;
        A2[k * AROW + jp0]     = pk_u32(v.x, v.y);
        A2[k * AROW + jp0 + 1] = pk_u32(v.z, v.w);
    }
    if (t < 128) {
        const int idx = 3072 + t;
        const float4 v = sv[12];
        const int k   = idx >> 4;
        const int jp0 = (idx & 15) * 2;
        A2[k * AROW + jp0]     = pk_u32(v.x, v.y);
        A2[k * AROW + jp0 + 1] = pk_u32(v.z, v.w);
    }
    __syncthreads();

    // ---- scores: thread t = key k; qk via uniform uint4 LDS broadcast ----
    if (t < SK) {
        float a0 = 0.f, a1 = 0.f, a2 = 0.f, a3 = 0.f;
        const int base = t * AROW;
        const uint4* qk4 = (const uint4*)qk4_s;
        #pragma unroll 8
        for (int jp = 0; jp < JP; ++jp) {
            const half2v av = u2h(A2[base + jp]);    // bank (k+jp)%32: free
            const uint4 q4 = qk4[jp];                // uniform addr -> broadcast
            a0 = DOT2(av, u2h(q4.x), a0);
            a1 = DOT2(av, u2h(q4.y), a1);
            a2 = DOT2(av, u2h(q4.z), a2);
            a3 = DOT2(av, u2h(q4.w), a3);
        }
        float4 s; s.x = a0; s.y = a1; s.z = a2; s.w = a3;
        p4_s[t] = s;                                  // ds_write_b128
    }
    __syncthreads();

    // ---- softmax: wave wv owns head wv; 200 = 3*64 + 8 ----
    {
        float* pf = (float*)p4_s;
        const int h = wv;
        const float s0 = pf[lane * 4 + h];
        const float s1 = pf[(lane + 64) * 4 + h];
        const float s2 = pf[(lane + 128) * 4 + h];
        const float s3 = (lane < SK - 192) ? pf[(lane + 192) * 4 + h] : -1e30f;
        float m = fmaxf(fmaxf(s0, s1), fmaxf(s2, s3));
        #pragma unroll
        for (int off = 32; off; off >>= 1) m = fmaxf(m, __shfl_xor(m, off));
        const float e0 = __expf(s0 - m);
        const float e1 = __expf(s1 - m);
        const float e2 = __expf(s2 - m);
        const float e3 = (lane < SK - 192) ? __expf(s3 - m) : 0.f;
        pf[lane * 4 + h]         = e0;
        pf[(lane + 64) * 4 + h]  = e1;
        pf[(lane + 128) * 4 + h] = e2;
        if (lane < SK - 192) pf[(lane + 192) * 4 + h] = e3;
        float sum = e0 + e1 + e2 + e3;
        #pragma unroll
        for (int off = 32; off; off >>= 1) sum += __shfl_xor(sum, off);
        if (lane == 0) invd_s[h] = 1.f / sum;
    }
    __syncthreads();

    // ---- w[h][j] = sum_k p[h][k]*A[k][j]; k range split across 4 waves ----
    {
        const int j  = lane;
        const int jp = j >> 1;
        const int k0 = wv * 50;
        float c0 = 0.f, c1 = 0.f, c2 = 0.f, c3 = 0.f;
        #pragma unroll 10
        for (int kk = 0; kk < 50; ++kk) {
            const int k = k0 + kk;
            const float4 p = p4_s[k];                 // uniform b128 broadcast
            const half2v av = u2h(A2[k * AROW + jp]); // 2-lane broadcast, free
            const float a = (j & 1) ? (float)av.y : (float)av.x;
            c0 = fmaf(p.x, a, c0);
            c1 = fmaf(p.y, a, c1);
            c2 = fmaf(p.z, a, c2);
            c3 = fmaf(p.w, a, c3);
        }
        float4 c; c.x = c0; c.y = c1; c.z = c2; c.w = c3;
        wpart[wv][j] = c;
    }
    __syncthreads();

    // ---- reduce partials, fold 1/denom ----
    if (t < 64) {
        const float4 r0 = wpart[0][t], r1 = wpart[1][t];
        const float4 r2 = wpart[2][t], r3 = wpart[3][t];
        float4 w;
        w.x = (r0.x + r1.x + r2.x + r3.x) * invd_s[0];
        w.y = (r0.y + r1.y + r2.y + r3.y) * invd_s[1];
        w.z = (r0.z + r1.z + r2.z + r3.z) * invd_s[2];
        w.w = (r0.w + r1.w + r2.w + r3.w) * invd_s[3];
        w4_s[t] = w;
    }
    __syncthreads();

    // ---- epilogue: out[b][o] = sum_j w[h][j] * V[j][o], o = h*16+d ----
    if (t < 64) {
        const int h = t >> 4;
        const float* wf = (const float*)w4_s;
        float acc = 0.f;
        #pragma unroll
        for (int j = 0; j < AIS; ++j)
            acc = fmaf(wf[j * 4 + h], Vw[j * HD + t], acc);
        out[(size_t)b * HD + t] = acc;
    }
}

// ---------------------------------------------------------------------------
extern "C" void kernel_launch(void* const* d_in, const int* in_sizes, int n_in,
                              void* d_out, int out_size, void* d_ws, size_t ws_size,
                              hipStream_t stream) {
    const float* query  = (const float*)d_in[0];   // [B,1,64]
    const float* action = (const float*)d_in[1];   // [B,200,64]
    const float* Qw     = (const float*)d_in[2];   // [64,64]
    const float* Kw     = (const float*)d_in[3];   // [64,64]
    const float* Vw     = (const float*)d_in[4];   // [64,64]
    float* outp = (float*)d_out;                   // [B,64]

    (void)d_ws; (void)ws_size;                     // NO workspace use (poison-fill test)

    const int B = in_sizes[0] / COL;               // 8192
    fused_attn_kernel<<<B, 256, 0, stream>>>(query, action, Qw, Kw, Vw, outp);
}